// Round 2
// baseline (867.998 us; speedup 1.0000x reference)
//
#include <hip/hip_runtime.h>

#define VOCAB 27
#define EMB   32
#define HID   64
#define BATCH 4096
#define TLEN  256
#define WPB   4     // waves (batch rows) per block

// tanh(x) = 1 - 2/(exp2(2*log2e*x) + 1)   -- all inline VALU, no libcall.
// v_exp_f32 + v_rcp_f32 are ~1 ulp; abs err ~1e-7, noise vs fp32 chain diffs.
__device__ __forceinline__ float fast_tanh(float x) {
    float t = __builtin_amdgcn_exp2f(x * 2.885390081777927f); // 2/ln(2)
    float r = __builtin_amdgcn_rcpf(t + 1.0f);
    return fmaf(-2.0f, r, 1.0f);
}

__global__ __launch_bounds__(256, 3) void rnn_fused(
    const int*   __restrict__ X,      // (B,T)
    const float* __restrict__ emb_w,  // (27,32)
    const float* __restrict__ start,  // (1,64)
    const float* __restrict__ rnn_w,  // (64,96)  [:, :32]=Wx  [:, 32:]=Wh
    const float* __restrict__ rnn_b,  // (64)
    const float* __restrict__ lm_w,   // (27,64)
    const float* __restrict__ lm_b,   // (27)
    float*       __restrict__ out)    // (B,T,27)
{
    __shared__ float table[VOCAB][HID];   // xp lookup: rnn_b + Wx . emb_w[v]
    __shared__ float hbuf[WPB][HID];      // per-wave h_{t-1} broadcast buffer
    __shared__ int   xrow[WPB][TLEN];     // per-wave token row

    const int tid  = threadIdx.x;
    const int lane = tid & 63;
    const int wave = tid >> 6;
    const int b    = blockIdx.x * WPB + wave;

    // Build the 27x64 xproj table once per block (collapses emb gather + xproj einsum).
    for (int f = tid; f < VOCAB * HID; f += 256) {
        const int v = f >> 6, i = f & 63;
        float s = rnn_b[i];
        #pragma unroll
        for (int e = 0; e < EMB; ++e)
            s += rnn_w[i * (EMB + HID) + e] * emb_w[v * EMB + e];
        table[v][i] = s;
    }
    // Stage this wave's token row into LDS (uniform broadcast reads in the loop).
    {
        const int* Xb = X + (size_t)b * TLEN;
        #pragma unroll
        for (int k = 0; k < TLEN / 64; ++k)
            xrow[wave][k * 64 + lane] = Xb[k * 64 + lane];
    }
    __syncthreads();

    // Wh row `lane` resident in 64 VGPRs (float4 x16, 16B-aligned: 96,32,4k all %4==0).
    float4 wh[16];
    #pragma unroll
    for (int k = 0; k < 16; ++k)
        wh[k] = *(const float4*)&rnn_w[lane * (EMB + HID) + EMB + 4 * k];

    // Logits split across lane halves: half 0 sums j<32, half 1 sums j>=32.
    // Each lane keeps only its 32-wide slice of lm_w (8 float4).
    const int vmod = lane & 31;
    const int vv   = vmod < VOCAB ? vmod : VOCAB - 1;
    const int half = lane >> 5;
    float4 lw[8];
    #pragma unroll
    for (int m = 0; m < 8; ++m)
        lw[m] = *(const float4*)&lm_w[vv * HID + half * 32 + 4 * m];
    const float lb = (half == 0 && vmod < VOCAB) ? lm_b[lane] : 0.0f;

    float h = start[lane];                    // h_{-1}
    float* outb = out + (size_t)b * TLEN * VOCAB;

    int   tok = xrow[wave][0];
    float xp  = table[tok][lane];             // xp for t=0

    for (int t = 0; t < TLEN; ++t) {
        // Prefetch next step's xp (uniform token broadcast -> per-lane table row).
        const int   tn    = (t + 1) & (TLEN - 1);   // wraps to dummy read at t=255
        const int   tok_n = xrow[wave][tn];
        const float xp_n  = table[tok_n][lane];

        // Publish h_{t-1}; wave-private buffer, lgkmcnt ordering within the wave.
        hbuf[wave][lane] = h;
        const float4* hb = (const float4*)&hbuf[wave][0];         // uniform addr
        const float4* hh = (const float4*)&hbuf[wave][half * 32]; // 2-addr bcast (free)

        // Recurrence: acc_lane = xp + sum_j Wh[lane][j] * h[j]   (uniform h via LDS bcast)
        float acc = xp;
        #pragma unroll
        for (int k = 0; k < 16; ++k) {
            const float4 h4 = hb[k];
            acc = fmaf(wh[k].x, h4.x, acc);
            acc = fmaf(wh[k].y, h4.y, acc);
            acc = fmaf(wh[k].z, h4.z, acc);
            acc = fmaf(wh[k].w, h4.w, acc);
        }

        // Logits of h_{t-1} (stored at t-1), half-sums per lane.
        float lg = lb;
        #pragma unroll
        for (int m = 0; m < 8; ++m) {
            const float4 h4 = hh[m];
            lg = fmaf(lw[m].x, h4.x, lg);
            lg = fmaf(lw[m].y, h4.y, lg);
            lg = fmaf(lw[m].z, h4.z, lg);
            lg = fmaf(lw[m].w, h4.w, lg);
        }
        lg += __shfl_xor(lg, 32, 64);
        if (t > 0 && lane < VOCAB)
            outb[(size_t)(t - 1) * VOCAB + lane] = lg;

        h  = fast_tanh(acc);   // h_t
        xp = xp_n;
    }

    // Final logits for t = T-1 from h_{T-1}.
    {
        hbuf[wave][lane] = h;
        const float4* hh = (const float4*)&hbuf[wave][half * 32];
        float lg = lb;
        #pragma unroll
        for (int m = 0; m < 8; ++m) {
            const float4 h4 = hh[m];
            lg = fmaf(lw[m].x, h4.x, lg);
            lg = fmaf(lw[m].y, h4.y, lg);
            lg = fmaf(lw[m].z, h4.z, lg);
            lg = fmaf(lw[m].w, h4.w, lg);
        }
        lg += __shfl_xor(lg, 32, 64);
        if (lane < VOCAB)
            outb[(size_t)(TLEN - 1) * VOCAB + lane] = lg;
    }
}

extern "C" void kernel_launch(void* const* d_in, const int* in_sizes, int n_in,
                              void* d_out, int out_size, void* d_ws, size_t ws_size,
                              hipStream_t stream) {
    const int*   X     = (const int*)  d_in[0];
    const float* emb_w = (const float*)d_in[1];
    const float* start = (const float*)d_in[2];
    const float* rnn_w = (const float*)d_in[3];
    const float* rnn_b = (const float*)d_in[4];
    const float* lm_w  = (const float*)d_in[5];
    const float* lm_b  = (const float*)d_in[6];
    float*       out   = (float*)d_out;

    dim3 grid(BATCH / WPB);
    dim3 block(256);
    rnn_fused<<<grid, block, 0, stream>>>(X, emb_w, start, rnn_w, rnn_b,
                                          lm_w, lm_b, out);
}

// Round 6
// 457.098 us; speedup vs baseline: 1.8989x; 1.8989x over previous
//
#include <hip/hip_runtime.h>

#define VOCAB 27
#define EMB   32
#define HID   64
#define BATCH 4096
#define TLEN  256
#define WPB   4     // waves (batch rows) per block

// tanh(x) = 1 - 2/(exp2(2*log2e*x) + 1)   -- inline VALU, no libcall.
__device__ __forceinline__ float fast_tanh(float x) {
    float t = __builtin_amdgcn_exp2f(x * 2.885390081777927f); // 2/ln2
    float r = __builtin_amdgcn_rcpf(t + 1.0f);
    return fmaf(-2.0f, r, 1.0f);
}

// Inline function, not a macro: a macro param named `w` captures the `.w`
// member token (R5 compile failure).
__device__ __forceinline__ void fma4(float& acc, const float4& a, const float4& b) {
    acc = fmaf(a.x, b.x, acc);
    acc = fmaf(a.y, b.y, acc);
    acc = fmaf(a.z, b.z, acc);
    acc = fmaf(a.w, b.w, acc);
}

__global__ __launch_bounds__(256)
__attribute__((amdgpu_waves_per_eu(2, 3)))   // pin: no occupancy-chasing spills
void rnn_fused(
    const int*   __restrict__ X,      // (B,T)
    const float* __restrict__ emb_w,  // (27,32)
    const float* __restrict__ start,  // (1,64)
    const float* __restrict__ rnn_w,  // (64,96)  [:, :32]=Wx  [:, 32:]=Wh
    const float* __restrict__ rnn_b,  // (64)
    const float* __restrict__ lm_w,   // (27,64)
    const float* __restrict__ lm_b,   // (27)
    float*       __restrict__ out)    // (B,T,27)
{
    __shared__ float table[VOCAB][HID];   // xp lookup: rnn_b + Wx . emb_w[v]
    __shared__ float hbuf[WPB][HID];      // per-wave h_{t-1} broadcast buffer
    __shared__ int   xrow[WPB][TLEN];     // per-wave token row

    const int tid  = threadIdx.x;
    const int lane = tid & 63;
    const int wave = tid >> 6;
    const int b    = blockIdx.x * WPB + wave;

    // Build the 27x64 xproj table once per block.
    for (int f = tid; f < VOCAB * HID; f += 256) {
        const int v = f >> 6, i = f & 63;
        float s = rnn_b[i];
        #pragma unroll
        for (int e = 0; e < EMB; ++e)
            s += rnn_w[i * (EMB + HID) + e] * emb_w[v * EMB + e];
        table[v][i] = s;
    }
    {
        const int* Xb = X + (size_t)b * TLEN;
        #pragma unroll
        for (int k = 0; k < TLEN / 64; ++k)
            xrow[wave][k * 64 + lane] = Xb[k * 64 + lane];
    }
    __syncthreads();

    // Wh row `lane`: 64 VGPRs.
    float4 wh[16];
    #pragma unroll
    for (int k = 0; k < 16; ++k)
        wh[k] = *(const float4*)&rnn_w[lane * (EMB + HID) + EMB + 4 * k];

    // Logits half-split: half 0 sums j<32, half 1 sums j>=32 (32 VGPRs).
    const int vmod = lane & 31;
    const int vv   = vmod < VOCAB ? vmod : VOCAB - 1;
    const int half = lane >> 5;
    float4 lw[8];
    #pragma unroll
    for (int m = 0; m < 8; ++m)
        lw[m] = *(const float4*)&lm_w[vv * HID + half * 32 + 4 * m];
    const float lb = (half == 0 && vmod < VOCAB) ? lm_b[lane] : 0.0f;

    float h = start[lane];                    // h_{-1}
    float* outb = out + (size_t)b * TLEN * VOCAB;
    float xp = table[xrow[wave][0]][lane];    // xp for t=0

    for (int t = 0; t < TLEN; ++t) {
        // Prefetch next xp (uniform token -> per-lane table row, conflict-free).
        const int   tok_n = xrow[wave][(t + 1) & (TLEN - 1)];
        const float xp_n  = table[tok_n][lane];

        // Publish h_{t-1}; wave-private buffer, compiler inserts lgkmcnt.
        hbuf[wave][lane] = h;
        const float4* hb = (const float4*)&hbuf[wave][0];         // uniform bcast
        const float4* hh = (const float4*)&hbuf[wave][half * 32]; // 2-addr bcast

        // 4 recurrence chains (depth 16) + 2 logit chains (depth 16).
        float a0 = xp, a1 = 0.0f, a2 = 0.0f, a3 = 0.0f;
        float l0 = lb, l1 = 0.0f;
        #pragma unroll
        for (int k = 0; k < 4; ++k) {
            const float4 h0 = hb[4 * k + 0];
            const float4 h1 = hb[4 * k + 1];
            const float4 h2 = hb[4 * k + 2];
            const float4 h3 = hb[4 * k + 3];
            fma4(a0, wh[4 * k + 0], h0);
            fma4(a1, wh[4 * k + 1], h1);
            fma4(a2, wh[4 * k + 2], h2);
            fma4(a3, wh[4 * k + 3], h3);
            const float4 g0 = hh[2 * k + 0];
            const float4 g1 = hh[2 * k + 1];
            fma4(l0, lw[2 * k + 0], g0);
            fma4(l1, lw[2 * k + 1], g1);
        }

        float lg = l0 + l1;
        lg += __shfl_xor(lg, 32, 64);
        if (t > 0 && lane < VOCAB)
            outb[(size_t)(t - 1) * VOCAB + lane] = lg;

        h  = fast_tanh((a0 + a1) + (a2 + a3));   // h_t
        xp = xp_n;
    }

    // Final logits for t = T-1 from h_{T-1}.
    {
        hbuf[wave][lane] = h;
        const float4* hh = (const float4*)&hbuf[wave][half * 32];
        float l0 = lb, l1 = 0.0f;
        #pragma unroll
        for (int k = 0; k < 4; ++k) {
            const float4 g0 = hh[2 * k + 0];
            const float4 g1 = hh[2 * k + 1];
            fma4(l0, lw[2 * k + 0], g0);
            fma4(l1, lw[2 * k + 1], g1);
        }
        float lg = l0 + l1;
        lg += __shfl_xor(lg, 32, 64);
        if (lane < VOCAB)
            outb[(size_t)(TLEN - 1) * VOCAB + lane] = lg;
    }
}

extern "C" void kernel_launch(void* const* d_in, const int* in_sizes, int n_in,
                              void* d_out, int out_size, void* d_ws, size_t ws_size,
                              hipStream_t stream) {
    const int*   X     = (const int*)  d_in[0];
    const float* emb_w = (const float*)d_in[1];
    const float* start = (const float*)d_in[2];
    const float* rnn_w = (const float*)d_in[3];
    const float* rnn_b = (const float*)d_in[4];
    const float* lm_w  = (const float*)d_in[5];
    const float* lm_b  = (const float*)d_in[6];
    float*       out   = (float*)d_out;

    dim3 grid(BATCH / WPB);
    dim3 block(256);
    rnn_fused<<<grid, block, 0, stream>>>(X, emb_w, start, rnn_w, rnn_b,
                                          lm_w, lm_b, out);
}